// Round 2
// baseline (290.383 us; speedup 1.0000x reference)
//
#include <hip/hip_runtime.h>
#include <hip/hip_bf16.h>

// n=8192 rows, d=256 feat, 10 classes.
// loss = mean_i log1p(exp(0.5/0.7) * A_i * B_i)
//   A_i = sum_{j: y_j!=y_i} exp(sim_ij/0.7), B_i = sum_{j!=i: y_j==y_i} exp(-sim_ij/0.7)
//   sim = rownorm(P) @ rownorm(P)^T  (symmetric!)
//
// R2 design: no LDS staging (data is L2-resident; K=256 too short to amortize
// barriers). Each lane global_load_dwordx4's its MFMA fragments directly,
// register-double-buffered -> barrier-free K-loop. Lower-triangle tiles only;
// off-diag tiles credit both row-side (reduce over 16 col-lanes) and col-side
// (reduce over 4 row-quads) via atomics into Aacc/Bacc.

#define NF 256
#define TINV (1.0f / 0.7f)

typedef __attribute__((ext_vector_type(8))) short short8;
typedef __attribute__((ext_vector_type(4))) float float4v;

// One wave per row: float4 load (64 lanes x 16B = 1KB row), normalize, bf16.
// Fused class histogram.
__global__ __launch_bounds__(256)
void k_prep(const float* __restrict__ P, unsigned short* __restrict__ Pn,
            const int* __restrict__ y, int* __restrict__ hist) {
    int wave = threadIdx.x >> 6, lane = threadIdx.x & 63;
    int row = blockIdx.x * 4 + wave;
    float4 v = *(const float4*)(P + (size_t)row * NF + lane * 4);
    float sq = v.x * v.x + v.y * v.y + v.z * v.z + v.w * v.w;
#pragma unroll
    for (int off = 32; off; off >>= 1) sq += __shfl_xor(sq, off, 64);
    float r = rsqrtf(sq);
    __hip_bfloat16 h0 = __float2bfloat16(v.x * r), h1 = __float2bfloat16(v.y * r),
                   h2 = __float2bfloat16(v.z * r), h3 = __float2bfloat16(v.w * r);
    ushort4 o = { *(unsigned short*)&h0, *(unsigned short*)&h1,
                  *(unsigned short*)&h2, *(unsigned short*)&h3 };
    *(ushort4*)(Pn + (size_t)row * NF + lane * 4) = o;
    if (lane == 0) atomicAdd(&hist[y[row] & 63], 1);
}

__global__ __launch_bounds__(256)
void k_main(const unsigned short* __restrict__ Pn, const int* __restrict__ y,
            float* __restrict__ Aacc, float* __restrict__ Bacc) {
    // triangular tile decode: bid -> (I,J), J<=I, 64 row-tiles of 128
    int bid = blockIdx.x;
    int I = (int)((sqrtf(8.0f * (float)bid + 1.0f) - 1.0f) * 0.5f);
    while ((I + 1) * (I + 2) / 2 <= bid) ++I;
    while (I * (I + 1) / 2 > bid) --I;
    const int J = bid - I * (I + 1) / 2;
    const int rb = I * 128, cb = J * 128;
    const bool offdiag = (I != J);

    __shared__ int yr[128], yc[128];
    const int tid = threadIdx.x;
    if (tid < 128) yr[tid] = y[rb + tid];
    else           yc[tid - 128] = y[cb + tid - 128];
    __syncthreads();

    const int lane = tid & 63, wave = tid >> 6;
    const int quad = lane >> 4, l15 = lane & 15;
    const int wr = wave >> 1, wc = wave & 1;  // 2x2 waves of 64x64

    // A-frag (16x16x32): m=l15, k=quad*8+j ; B-frag identical on B^T rows.
    const unsigned short* pa = Pn + (size_t)(rb + wr * 64 + l15) * NF + quad * 8;
    const unsigned short* pb = Pn + (size_t)(cb + wc * 64 + l15) * NF + quad * 8;

    float4v acc[4][4];
#pragma unroll
    for (int a = 0; a < 4; ++a)
#pragma unroll
        for (int b = 0; b < 4; ++b) acc[a][b] = (float4v){0.f, 0.f, 0.f, 0.f};

    short8 fa[2][4], fb[2][4];
#pragma unroll
    for (int t = 0; t < 4; ++t) {
        fa[0][t] = *(const short8*)(pa + t * 16 * NF);
        fb[0][t] = *(const short8*)(pb + t * 16 * NF);
    }
#pragma unroll
    for (int ks = 0; ks < 8; ++ks) {          // K=256 in 8 steps of 32
        const int cu = ks & 1, nx = cu ^ 1;
        if (ks < 7) {
#pragma unroll
            for (int t = 0; t < 4; ++t) {
                fa[nx][t] = *(const short8*)(pa + (ks + 1) * 32 + t * 16 * NF);
                fb[nx][t] = *(const short8*)(pb + (ks + 1) * 32 + t * 16 * NF);
            }
        }
#pragma unroll
        for (int tr = 0; tr < 4; ++tr)
#pragma unroll
            for (int tc = 0; tc < 4; ++tc)
                acc[tr][tc] = __builtin_amdgcn_mfma_f32_16x16x32_bf16(
                    fa[cu][tr], fb[cu][tc], acc[tr][tc], 0, 0, 0);
    }

    // Epilogue. C/D: col=l15, row=quad*4+reg.
    float colA[4] = {0.f, 0.f, 0.f, 0.f}, colB[4] = {0.f, 0.f, 0.f, 0.f};
    const int gr0 = rb + wr * 64 + quad * 4;
#pragma unroll
    for (int tr = 0; tr < 4; ++tr) {
        float rowA[4] = {0.f, 0.f, 0.f, 0.f}, rowB[4] = {0.f, 0.f, 0.f, 0.f};
        int yi[4];
#pragma unroll
        for (int r = 0; r < 4; ++r) yi[r] = yr[wr * 64 + tr * 16 + quad * 4 + r];
#pragma unroll
        for (int tc = 0; tc < 4; ++tc) {
            const int jl = wc * 64 + tc * 16 + l15;
            const int yj = yc[jl], gj = cb + jl;
#pragma unroll
            for (int r = 0; r < 4; ++r) {
                float s = acc[tr][tc][r];
                bool same = (yi[r] == yj);
                int gi = gr0 + tr * 16 + r;
                float e = __expf((same ? -s : s) * TINV);
                float ea = same ? 0.f : e;
                float eb = (same && gi != gj) ? e : 0.f;
                rowA[r] += ea; rowB[r] += eb;
                colA[tc] += ea; colB[tc] += eb;
            }
        }
#pragma unroll
        for (int r = 0; r < 4; ++r) {
#pragma unroll
            for (int off = 1; off < 16; off <<= 1) {
                rowA[r] += __shfl_xor(rowA[r], off, 64);
                rowB[r] += __shfl_xor(rowB[r], off, 64);
            }
        }
        if (l15 == 0) {
#pragma unroll
            for (int r = 0; r < 4; ++r) {
                int gi = gr0 + tr * 16 + r;
                atomicAdd(&Aacc[gi], rowA[r]);
                atomicAdd(&Bacc[gi], rowB[r]);
            }
        }
    }
    if (offdiag) {  // credit column rows (sim_ji == sim_ij)
#pragma unroll
        for (int tc = 0; tc < 4; ++tc) {
            colA[tc] += __shfl_xor(colA[tc], 16, 64);
            colA[tc] += __shfl_xor(colA[tc], 32, 64);
            colB[tc] += __shfl_xor(colB[tc], 16, 64);
            colB[tc] += __shfl_xor(colB[tc], 32, 64);
        }
        if (quad == 0) {
#pragma unroll
            for (int tc = 0; tc < 4; ++tc) {
                int gj = cb + wc * 64 + tc * 16 + l15;
                atomicAdd(&Aacc[gj], colA[tc]);
                atomicAdd(&Bacc[gj], colB[tc]);
            }
        }
    }
}

__global__ __launch_bounds__(256)
void k_final(const float* __restrict__ Aacc, const float* __restrict__ Bacc,
             const int* __restrict__ y, const int* __restrict__ hist,
             float* __restrict__ out, int n) {
    const float M = __expf(0.5f * TINV);
    float s = 0.f;
    for (int i = blockIdx.x * blockDim.x + threadIdx.x; i < n;
         i += gridDim.x * blockDim.x) {
        int c = hist[y[i] & 63];
        float a = (n - c) > 0 ? Aacc[i] : 1.0f;
        float b = (c - 1) > 0 ? Bacc[i] : 1.0f;
        s += log1pf(M * a * b);
    }
#pragma unroll
    for (int off = 32; off; off >>= 1) s += __shfl_xor(s, off, 64);
    __shared__ float red[4];
    if ((threadIdx.x & 63) == 0) red[threadIdx.x >> 6] = s;
    __syncthreads();
    if (threadIdx.x == 0)
        atomicAdd(out, (red[0] + red[1] + red[2] + red[3]) / (float)n);
}

extern "C" void kernel_launch(void* const* d_in, const int* in_sizes, int n_in,
                              void* d_out, int out_size, void* d_ws, size_t ws_size,
                              hipStream_t stream) {
    const float* P = (const float*)d_in[0];
    const int* y   = (const int*)d_in[1];
    float* out     = (float*)d_out;
    const int n = in_sizes[1];  // 8192

    // ws: Pn bf16 [n*256] | Aacc f32 [n] | Bacc f32 [n] | hist i32 [64]
    unsigned short* Pn = (unsigned short*)d_ws;
    float* Aacc = (float*)((char*)d_ws + (size_t)n * NF * 2);
    float* Bacc = Aacc + n;
    int* hist   = (int*)(Bacc + n);

    hipMemsetAsync(Aacc, 0, (size_t)2 * n * sizeof(float) + 64 * sizeof(int), stream);
    hipMemsetAsync(out, 0, sizeof(float), stream);
    k_prep<<<n / 4, 256, 0, stream>>>(P, Pn, y, hist);
    const int ntile = n / 128;                       // 64
    const int nblk = ntile * (ntile + 1) / 2;        // 2080
    k_main<<<nblk, 256, 0, stream>>>(Pn, y, Aacc, Bacc);
    k_final<<<16, 256, 0, stream>>>(Aacc, Bacc, y, hist, out, n);
}

// Round 3
// 241.716 us; speedup vs baseline: 1.2013x; 1.2013x over previous
//
#include <hip/hip_runtime.h>
#include <hip/hip_bf16.h>

// n=8192 rows, d=256 feat, 10 classes.
// loss = mean_i log1p(exp(0.5/0.7) * A_i * B_i)
//   A_i = sum_{j: y_j!=y_i} exp(sim_ij/0.7), B_i = sum_{j!=i: y_j==y_i} exp(-sim_ij/0.7)
//   sim = rownorm(P) @ rownorm(P)^T
//
// R3: atomic-storm fix. Full matrix (no col-credit machinery), block =
// 128-row panel x 512-col strip (4 inner 128-col tiles). Row A/B partial
// sums accumulate in REGISTERS across the strip; one butterfly + LDS merge
// per block; 256 global atomics per block (262K total vs R2's 1.33M).
// Single-buffered MFMA frags under __launch_bounds__(256,3) to avoid the
// R2 spill risk (VGPR cap ~170, est ~165). 3 dispatches, no memsets.

#define NF 256
#define TINV (1.0f / 0.7f)

typedef __attribute__((ext_vector_type(8))) short short8;
typedef __attribute__((ext_vector_type(4))) float float4v;

// One wave per row: normalize to bf16. Also zeroes the accumulators.
__global__ __launch_bounds__(256)
void k_prep(const float* __restrict__ P, unsigned short* __restrict__ Pn,
            float* __restrict__ AB) {  // AB = Aacc||Bacc, 2n floats
    int wave = threadIdx.x >> 6, lane = threadIdx.x & 63;
    int row = blockIdx.x * 4 + wave;
    if (threadIdx.x < 8) AB[blockIdx.x * 8 + threadIdx.x] = 0.f;
    float4 v = *(const float4*)(P + (size_t)row * NF + lane * 4);
    float sq = v.x * v.x + v.y * v.y + v.z * v.z + v.w * v.w;
#pragma unroll
    for (int off = 32; off; off >>= 1) sq += __shfl_xor(sq, off, 64);
    float r = rsqrtf(sq);
    __hip_bfloat16 h0 = __float2bfloat16(v.x * r), h1 = __float2bfloat16(v.y * r),
                   h2 = __float2bfloat16(v.z * r), h3 = __float2bfloat16(v.w * r);
    ushort4 o = { *(unsigned short*)&h0, *(unsigned short*)&h1,
                  *(unsigned short*)&h2, *(unsigned short*)&h3 };
    *(ushort4*)(Pn + (size_t)row * NF + lane * 4) = o;
}

__global__ __launch_bounds__(256, 3)
void k_main(const unsigned short* __restrict__ Pn, const int* __restrict__ y,
            float* __restrict__ Aacc, float* __restrict__ Bacc) {
    const int I = blockIdx.x >> 4;          // row panel (64)
    const int c = blockIdx.x & 15;          // col chunk: cols [c*512, c*512+512)
    const int rb = I * 128, cb0 = c * 512;

    __shared__ int yr[128];
    __shared__ int yc[512];
    __shared__ float mA[128], mB[128];

    const int tid = threadIdx.x;
    if (tid < 128) yr[tid] = y[rb + tid];
    yc[tid] = y[cb0 + tid];
    yc[tid + 256] = y[cb0 + 256 + tid];
    __syncthreads();

    const int lane = tid & 63, wave = tid >> 6;
    const int quad = lane >> 4, l15 = lane & 15;
    const int wr = wave >> 1, wc = wave & 1;     // 2x2 waves, 64x64 each

    // A-frag (16x16x32): m=l15, k=quad*8+j. Same for B on row-major Pn.
    const unsigned short* pa = Pn + (size_t)(rb + wr * 64 + l15) * NF + quad * 8;

    int yi[4][4];
#pragma unroll
    for (int tr = 0; tr < 4; ++tr)
#pragma unroll
        for (int r = 0; r < 4; ++r) yi[tr][r] = yr[wr * 64 + tr * 16 + quad * 4 + r];

    float rowA[4][4], rowB[4][4];
#pragma unroll
    for (int tr = 0; tr < 4; ++tr)
#pragma unroll
        for (int r = 0; r < 4; ++r) { rowA[tr][r] = 0.f; rowB[tr][r] = 0.f; }

#pragma unroll 1
    for (int jt = 0; jt < 4; ++jt) {
        const int cb = cb0 + jt * 128;
        const unsigned short* pb = Pn + (size_t)(cb + wc * 64 + l15) * NF + quad * 8;

        float4v acc[4][4];
#pragma unroll
        for (int a = 0; a < 4; ++a)
#pragma unroll
            for (int b = 0; b < 4; ++b) acc[a][b] = (float4v){0.f, 0.f, 0.f, 0.f};

#pragma unroll
        for (int ks = 0; ks < 8; ++ks) {
            short8 fa[4], fb[4];
#pragma unroll
            for (int t = 0; t < 4; ++t) {
                fa[t] = *(const short8*)(pa + ks * 32 + (size_t)t * 16 * NF);
                fb[t] = *(const short8*)(pb + ks * 32 + (size_t)t * 16 * NF);
            }
#pragma unroll
            for (int tr = 0; tr < 4; ++tr)
#pragma unroll
                for (int tc = 0; tc < 4; ++tc)
                    acc[tr][tc] = __builtin_amdgcn_mfma_f32_16x16x32_bf16(
                        fa[tr], fb[tc], acc[tr][tc], 0, 0, 0);
        }

        // Fused epilogue into register row-accumulators. C/D: col=l15, row=quad*4+reg.
#pragma unroll
        for (int tc = 0; tc < 4; ++tc) {
            const int jl = jt * 128 + wc * 64 + tc * 16 + l15;
            const int yj = yc[jl];
            const int gj = cb0 + jl;
#pragma unroll
            for (int tr = 0; tr < 4; ++tr) {
                const int gi0 = rb + wr * 64 + tr * 16 + quad * 4;
#pragma unroll
                for (int r = 0; r < 4; ++r) {
                    float s = acc[tr][tc][r];
                    bool same = (yi[tr][r] == yj);
                    float e = __expf(s * (same ? -TINV : TINV));
                    rowA[tr][r] += same ? 0.f : e;
                    rowB[tr][r] += (same && (gi0 + r != gj)) ? e : 0.f;
                }
            }
        }
    }

    // Reduce across the 16 column-lanes (l15), then merge the wc pair via LDS.
#pragma unroll
    for (int tr = 0; tr < 4; ++tr)
#pragma unroll
        for (int r = 0; r < 4; ++r) {
#pragma unroll
            for (int off = 1; off < 16; off <<= 1) {
                rowA[tr][r] += __shfl_xor(rowA[tr][r], off, 64);
                rowB[tr][r] += __shfl_xor(rowB[tr][r], off, 64);
            }
        }
    if (wc == 0 && l15 == 0) {
#pragma unroll
        for (int tr = 0; tr < 4; ++tr)
#pragma unroll
            for (int r = 0; r < 4; ++r) {
                int lr = wr * 64 + tr * 16 + quad * 4 + r;
                mA[lr] = rowA[tr][r]; mB[lr] = rowB[tr][r];
            }
    }
    __syncthreads();
    if (wc == 1 && l15 == 0) {
#pragma unroll
        for (int tr = 0; tr < 4; ++tr)
#pragma unroll
            for (int r = 0; r < 4; ++r) {
                int lr = wr * 64 + tr * 16 + quad * 4 + r;
                atomicAdd(&Aacc[rb + lr], rowA[tr][r] + mA[lr]);
                atomicAdd(&Bacc[rb + lr], rowB[tr][r] + mB[lr]);
            }
    }
}

// Single block: builds the class histogram in LDS, computes the mean loss,
// writes out[0] directly (no memset, no global atomics).
__global__ __launch_bounds__(1024)
void k_final(const float* __restrict__ Aacc, const float* __restrict__ Bacc,
             const int* __restrict__ y, float* __restrict__ out, int n) {
    __shared__ int hist[16];
    __shared__ float red[16];
    const int tid = threadIdx.x;
    if (tid < 16) hist[tid] = 0;
    __syncthreads();
    for (int i = tid; i < n; i += 1024) atomicAdd(&hist[y[i] & 15], 1);
    __syncthreads();
    const float M = __expf(0.5f * TINV);
    float s = 0.f;
    for (int i = tid; i < n; i += 1024) {
        int cc = hist[y[i] & 15];
        float a = (n - cc) > 0 ? Aacc[i] : 1.0f;
        float b = (cc - 1) > 0 ? Bacc[i] : 1.0f;
        s += log1pf(M * a * b);
    }
#pragma unroll
    for (int off = 32; off; off >>= 1) s += __shfl_xor(s, off, 64);
    if ((tid & 63) == 0) red[tid >> 6] = s;
    __syncthreads();
    if (tid == 0) {
        float t = 0.f;
#pragma unroll
        for (int w = 0; w < 16; ++w) t += red[w];
        out[0] = t / (float)n;
    }
}

extern "C" void kernel_launch(void* const* d_in, const int* in_sizes, int n_in,
                              void* d_out, int out_size, void* d_ws, size_t ws_size,
                              hipStream_t stream) {
    const float* P = (const float*)d_in[0];
    const int* y   = (const int*)d_in[1];
    float* out     = (float*)d_out;
    const int n = in_sizes[1];  // 8192

    // ws: Pn bf16 [n*256] | Aacc f32 [n] | Bacc f32 [n]
    unsigned short* Pn = (unsigned short*)d_ws;
    float* Aacc = (float*)((char*)d_ws + (size_t)n * NF * 2);
    float* Bacc = Aacc + n;

    k_prep<<<n / 4, 256, 0, stream>>>(P, Pn, Aacc);
    k_main<<<(n / 128) * 16, 256, 0, stream>>>(Pn, y, Aacc, Bacc);
    k_final<<<1, 1024, 0, stream>>>(Aacc, Bacc, y, out, n);
}